// Round 20
// baseline (100.001 us; speedup 1.0000x reference)
//
#include <hip/hip_runtime.h>
#include <hip/hip_bf16.h>
#include <stdint.h>

#define D_MODEL 1024
#define NHEADS  16
#define HDIM    64
#define BB      2
#define TT      2048
#define MROWS   (BB*TT)      // 4096
#define GK      1024         // reduction dim for all projections

typedef __bf16 bf16_8 __attribute__((ext_vector_type(8)));
typedef __bf16 bf16_4 __attribute__((ext_vector_type(4)));
typedef float  f32x4  __attribute__((ext_vector_type(4)));
typedef unsigned short u16;

__device__ __forceinline__ u16 f2bf(float f) {
    union { float f; uint32_t u; } c; c.f = f;
    uint32_t u = c.u;
    uint32_t r = (u + 0x7FFFu + ((u >> 16) & 1u)) >> 16;
    return (u16)r;
}
__device__ __forceinline__ uint32_t pk2bf(float a, float b) {
    return (uint32_t)f2bf(a) | ((uint32_t)f2bf(b) << 16);
}

__device__ __forceinline__ void gload16(const void* g, void* l) {
    __builtin_amdgcn_global_load_lds(
        (const __attribute__((address_space(1))) unsigned int*)g,
        (__attribute__((address_space(3))) unsigned int*)l,
        16, 0, 0);
}

// ---------------------------------------------------------------- convert
__global__ __launch_bounds__(256) void cvtk(
    const float* __restrict__ x,  const float* __restrict__ wq,
    const float* __restrict__ wk, const float* __restrict__ wv,
    const float* __restrict__ wo, const unsigned char* __restrict__ mk,
    u16* __restrict__ xb,  u16* __restrict__ wqb, u16* __restrict__ wkb,
    u16* __restrict__ wvb, u16* __restrict__ wob, uint32_t* __restrict__ pmb)
{
    int z = blockIdx.y;
    if (z == 5) {   // pack padding mask bits: pmb[b*64 + i], bit j = mask[b][32i+j]
        int gi = blockIdx.x*256 + threadIdx.x;
        if (gi < BB*TT/32) {
            uint32_t wv = 0;
            #pragma unroll
            for (int j = 0; j < 32; ++j)
                wv |= (mk[gi*32 + j] ? 1u : 0u) << j;
            pmb[gi] = wv;
        }
        return;
    }
    const float* in; u16* out; int n4;
    switch (z) {
        case 0: in = x;  out = xb;  n4 = MROWS*D_MODEL/4; break;
        case 1: in = wq; out = wqb; n4 = D_MODEL*D_MODEL/4; break;
        case 2: in = wk; out = wkb; n4 = D_MODEL*D_MODEL/4; break;
        case 3: in = wv; out = wvb; n4 = D_MODEL*D_MODEL/4; break;
        default: in = wo; out = wob; n4 = D_MODEL*D_MODEL/4; break;
    }
    for (int i = blockIdx.x*256 + threadIdx.x; i < n4; i += 1024*256) {
        float4 v = ((const float4*)in)[i];
        uint2 pk;
        pk.x = pk2bf(v.x, v.y);
        pk.y = pk2bf(v.z, v.w);
        ((uint2*)out)[i] = pk;
    }
}

// ---------------------------------------------------------------- fused QKV GEMM
// Block computes the SAME 128x64 output tile of Q, K, and V^T: A (x) staged
// once per K-step, shared by all three weight panels. 512 blocks = 2/CU.
__global__ __launch_bounds__(256) void gemm_qkv(
    const u16* __restrict__ xb,
    const u16* __restrict__ wqb, const u16* __restrict__ wkb, const u16* __restrict__ wvb,
    u16* __restrict__ Qb, u16* __restrict__ Kb, u16* __restrict__ VTb)
{
    __shared__ u16 As[128*64];        // 16 KB
    __shared__ u16 Bs[3][64*64];      // 24 KB
    const int tid  = threadIdx.x;
    const int lane = tid & 63, w = tid >> 6;
    const int g = lane >> 4, lr = lane & 15;
    const int xcd = blockIdx.x & 7, q_ = blockIdx.x >> 3;
    const int bn = q_ & 15, bm = (q_ >> 4)*8 + xcd;
    const int m0 = bm * 128, n0 = bn * 64;
    const u16* Wz[3] = { wqb, wkb, wvb };

    f32x4 acc[3][2][4];
    #pragma unroll
    for (int z = 0; z < 3; ++z)
        #pragma unroll
        for (int i = 0; i < 2; ++i)
            #pragma unroll
            for (int j = 0; j < 4; ++j)
                acc[z][i][j] = f32x4{0.f, 0.f, 0.f, 0.f};

    for (int kt = 0; kt < 16; ++kt) {
        int k0 = kt*64;
        #pragma unroll
        for (int r = 0; r < 4; ++r) {
            int o   = r*256 + tid;
            int row = o >> 3;
            int lc  = (o & 7) ^ (row & 7);
            gload16(xb + (size_t)(m0+row)*GK + k0 + lc*8,
                    (char*)As + (size_t)(r*256 + w*64)*16);
        }
        #pragma unroll
        for (int z = 0; z < 3; ++z)
            #pragma unroll
            for (int r = 0; r < 2; ++r) {
                int o   = r*256 + tid;
                int row = o >> 3;
                int lc  = (o & 7) ^ (row & 7);
                gload16(Wz[z] + (size_t)(n0+row)*GK + k0 + lc*8,
                        (char*)&Bs[z][0] + (size_t)(r*256 + w*64)*16);
            }
        __syncthreads();
        #pragma unroll
        for (int ks = 0; ks < 2; ++ks) {
            bf16_8 af[2];
            #pragma unroll
            for (int mt = 0; mt < 2; ++mt) {
                int row = w*32 + mt*16 + lr;
                int ch  = (ks*4 + g) ^ (row & 7);
                af[mt] = *(const bf16_8*)((const char*)As + row*128 + ch*16);
            }
            #pragma unroll
            for (int z = 0; z < 3; ++z) {
                bf16_8 bfr[4];
                #pragma unroll
                for (int nt = 0; nt < 4; ++nt) {
                    int row = nt*16 + lr;
                    int ch  = (ks*4 + g) ^ (row & 7);
                    bfr[nt] = *(const bf16_8*)((const char*)&Bs[z][0] + row*128 + ch*16);
                }
                #pragma unroll
                for (int mt = 0; mt < 2; ++mt)
                    #pragma unroll
                    for (int nt = 0; nt < 4; ++nt) {
                        if (z == 2)
                            acc[2][mt][nt] = __builtin_amdgcn_mfma_f32_16x16x32_bf16(
                                bfr[nt], af[mt], acc[2][mt][nt], 0, 0, 0);
                        else
                            acc[z][mt][nt] = __builtin_amdgcn_mfma_f32_16x16x32_bf16(
                                af[mt], bfr[nt], acc[z][mt][nt], 0, 0, 0);
                    }
            }
        }
        __syncthreads();
    }

    #pragma unroll
    for (int mt = 0; mt < 2; ++mt)
        #pragma unroll
        for (int nt = 0; nt < 4; ++nt)
            #pragma unroll
            for (int r = 0; r < 4; ++r) {
                int row = m0 + w*32 + mt*16 + g*4 + r;
                int col = n0 + nt*16 + lr;
                int b = row >> 11, t = row & (TT-1);
                int h = col >> 6,  d = col & 63;
                size_t qi = (((size_t)(b*NHEADS + h)*TT + t)*HDIM + d);
                Qb[qi] = f2bf(acc[0][mt][nt][r] * 0.18033688f);   // (1/8)*log2(e)
                Kb[qi] = f2bf(acc[1][mt][nt][r]);
                int nrow = n0 + nt*16 + g*4 + r;
                int mcol = m0 + w*32 + mt*16 + lr;
                int hv = nrow >> 6,  dv = nrow & 63;
                int bv = mcol >> 11, tv = mcol & (TT-1);
                VTb[(((size_t)(bv*NHEADS + hv)*HDIM + dv)*TT + tv)] = f2bf(acc[2][mt][nt][r]);
            }
}

// ---------------------------------------------------------------- out GEMM
// C(128x64) f32 tile of AO(4096x1024) * Wo(1024x1024)^T. 512 blocks = 2/CU.
__global__ __launch_bounds__(256) void gemm_out(
    const u16* __restrict__ AOb, const u16* __restrict__ wob, float* __restrict__ out)
{
    __shared__ u16 As[128*64];
    __shared__ u16 Bs[64*64];
    const int tid  = threadIdx.x;
    const int lane = tid & 63, w = tid >> 6;
    const int g = lane >> 4, lr = lane & 15;
    const int xcd = blockIdx.x & 7, q_ = blockIdx.x >> 3;
    const int bn = q_ & 15, bm = (q_ >> 4)*8 + xcd;
    const int m0 = bm * 128, n0 = bn * 64;

    f32x4 acc[2][4];
    #pragma unroll
    for (int i = 0; i < 2; ++i)
        #pragma unroll
        for (int j = 0; j < 4; ++j)
            acc[i][j] = f32x4{0.f, 0.f, 0.f, 0.f};

    for (int kt = 0; kt < 16; ++kt) {
        int k0 = kt*64;
        #pragma unroll
        for (int r = 0; r < 4; ++r) {
            int o   = r*256 + tid;
            int row = o >> 3;
            int lc  = (o & 7) ^ (row & 7);
            gload16(AOb + (size_t)(m0+row)*GK + k0 + lc*8,
                    (char*)As + (size_t)(r*256 + w*64)*16);
        }
        #pragma unroll
        for (int r = 0; r < 2; ++r) {
            int o   = r*256 + tid;
            int row = o >> 3;
            int lc  = (o & 7) ^ (row & 7);
            gload16(wob + (size_t)(n0+row)*GK + k0 + lc*8,
                    (char*)Bs + (size_t)(r*256 + w*64)*16);
        }
        __syncthreads();
        #pragma unroll
        for (int ks = 0; ks < 2; ++ks) {
            bf16_8 af[2], bfr[4];
            #pragma unroll
            for (int mt = 0; mt < 2; ++mt) {
                int row = w*32 + mt*16 + lr;
                int ch  = (ks*4 + g) ^ (row & 7);
                af[mt] = *(const bf16_8*)((const char*)As + row*128 + ch*16);
            }
            #pragma unroll
            for (int nt = 0; nt < 4; ++nt) {
                int row = nt*16 + lr;
                int ch  = (ks*4 + g) ^ (row & 7);
                bfr[nt] = *(const bf16_8*)((const char*)Bs + row*128 + ch*16);
            }
            #pragma unroll
            for (int mt = 0; mt < 2; ++mt)
                #pragma unroll
                for (int nt = 0; nt < 4; ++nt)
                    acc[mt][nt] = __builtin_amdgcn_mfma_f32_16x16x32_bf16(
                        af[mt], bfr[nt], acc[mt][nt], 0, 0, 0);
        }
        __syncthreads();
    }

    #pragma unroll
    for (int mt = 0; mt < 2; ++mt)
        #pragma unroll
        for (int nt = 0; nt < 4; ++nt)
            #pragma unroll
            for (int r = 0; r < 4; ++r) {
                int row = m0 + w*32 + mt*16 + g*4 + r;
                int col = n0 + nt*16 + lr;
                out[(size_t)row*D_MODEL + col] = acc[mt][nt][r];
            }
}

// ---------------------------------------------------------------- attention
// Round-17 skeleton with K double-buffer (depth-1): LDS ~50.7 KB -> 3
// blocks/CU = 24 waves/CU (+50% TLP vs depth-2's 2 blocks/CU).
// grid (32 bh, 16 pairs) = 512 blocks of 8 waves; wave owns ONE 16-row
// q-group (waves 0-3 heavy qtH=31-p, 4-7 light p); pair-balanced.
// Per iter: wait vmcnt(0) [K(t),V(t) landed] -> barrier -> stage K(t+1),
// V(t+1) -> compute(t). Max-free exp2 softmax; scalar mask loads.
__global__ __launch_bounds__(512, 4) void attn_fwd(
    const u16* __restrict__ Qb, const u16* __restrict__ Kb,
    const u16* __restrict__ VTb, const uint32_t* __restrict__ pmb,
    u16* __restrict__ AO)
{
    __shared__ u16 Ks[2][64*64];      // 16 KB
    __shared__ u16 Vs[2][64*64];      // 16 KB
    __shared__ u16 Pl[8][1152];       // 18 KB per-wave P / epilogue scratch

    const int tid = threadIdx.x, lane = tid & 63, w = tid >> 6;
    const int g = lane >> 4, lr = lane & 15;
    const int bh = blockIdx.x, yb = blockIdx.y;
    const int p  = (yb < 8) ? yb : 23 - yb;          // pair remap: CU gets (p,15-p)
    const int b = bh >> 4, h = bh & 15;
    const int qtH = 31 - p;
    const bool heavy = (w < 4);
    const int qlo = heavy ? (qtH*64 + w*16) : (p*64 + (w-4)*16);
    const int ta  = heavy ? qtH : p;                 // wave's last kv tile
    const int nt  = qtH + 1;

    const u16* Qh = Qb  + (size_t)bh*TT*HDIM;
    const u16* Kh = Kb  + (size_t)bh*TT*HDIM;
    const u16* Vh = VTb + (size_t)bh*HDIM*TT;
    const uint32_t* pmt = pmb + b*(TT/32);
    char* Pw = (char*)&Pl[w][0];

    // Q B-frags (pre-scaled by log2e/8): qf[dc] = Q[qlo+lr][dc*32+g*8..]
    bf16_8 qf[2];
    #pragma unroll
    for (int dc = 0; dc < 2; ++dc)
        qf[dc] = *(const bf16_8*)(Qh + (size_t)(qlo+lr)*HDIM + dc*32 + g*8);

    f32x4 o[4];                       // O^T: o[dt][r] = O[dt*16+4g+r][q=qlo+lr]
    #pragma unroll
    for (int i = 0; i < 4; ++i) o[i] = f32x4{0.f, 0.f, 0.f, 0.f};
    float l_run = 0.f;

    // cooperative stages: 512 threads x 16B = one 8KB tile per call
    auto STAGE_K = [&](int t, int buf) {
        int kv0 = t*64;
        int row = tid >> 3;                        // 0..63 (kv)
        int lc  = (tid & 7) ^ (row & 7);
        gload16(Kh + (size_t)(kv0+row)*HDIM + lc*8,
                (char*)&Ks[buf][0] + (size_t)(w*64)*16);
    };
    auto STAGE_V = [&](int t, int buf) {
        int kv0 = t*64;
        int row = tid >> 3;                        // 0..63 (d)
        int lc  = (tid & 7) ^ (row & 7);
        gload16(Vh + (size_t)row*TT + kv0 + lc*8,
                (char*)&Vs[buf][0] + (size_t)(w*64)*16);
    };

    // prologue: K0, V0 in flight
    STAGE_K(0, 0);
    STAGE_V(0, 0);

    for (int t = 0; t < nt; ++t) {
        asm volatile("s_waitcnt vmcnt(0) lgkmcnt(0)" ::: "memory");
        __builtin_amdgcn_s_barrier();
        if (t + 1 < nt) { STAGE_K(t+1, (t+1) & 1); STAGE_V(t+1, (t+1) & 1); }

        if (t <= ta) {
            const int kv0 = t*64;
            const u16* Kc = &Ks[t & 1][0];
            const u16* Vc = &Vs[t & 1][0];
            // wave-uniform mask words (scalar loads; latency hides under QK)
            uint32_t mw0 = pmt[2*t], mw1 = pmt[2*t+1];

            // ---- QK^T swapped: s[kvb] lane: q=qlo+lr, kv=kv0+16kvb+4g+reg
            f32x4 s[4];
            __builtin_amdgcn_s_setprio(1);
            #pragma unroll
            for (int kvb = 0; kvb < 4; ++kvb) {
                int row = kvb*16 + lr;
                int sw  = row & 7;
                bf16_8 k0 = *(const bf16_8*)(Kc + row*64 + ((g    ) ^ sw)*8);
                bf16_8 k1 = *(const bf16_8*)(Kc + row*64 + ((4 + g) ^ sw)*8);
                f32x4 z = f32x4{0.f, 0.f, 0.f, 0.f};
                z = __builtin_amdgcn_mfma_f32_16x16x32_bf16(k0, qf[0], z, 0, 0, 0);
                z = __builtin_amdgcn_mfma_f32_16x16x32_bf16(k1, qf[1], z, 0, 0, 0);
                s[kvb] = z;
            }
            __builtin_amdgcn_s_setprio(0);

            // ---- V^T A-frags (LDS; latency hides under softmax)
            bf16_8 vf[4][2];
            #pragma unroll
            for (int dt = 0; dt < 4; ++dt)
                #pragma unroll
                for (int hh = 0; hh < 2; ++hh)
                    vf[dt][hh] = *(const bf16_8*)(Vc + (dt*16+lr)*64 + ((hh*4+g) ^ (lr&7))*8);

            // ---- padding mask (skipped when all-clear)
            if (mw0 | mw1) {
                uint64_t m64 = (uint64_t)mw0 | ((uint64_t)mw1 << 32);
                #pragma unroll
                for (int kvb = 0; kvb < 4; ++kvb) {
                    uint32_t nib = (uint32_t)(m64 >> (kvb*16 + 4*g)) & 0xFu;
                    #pragma unroll
                    for (int r = 0; r < 4; ++r)
                        if ((nib >> r) & 1) s[kvb][r] = -1e30f;
                }
            }
            // ---- causal mask (diagonal tile only)
            if (t == ta) {
                int q = qlo + lr;
                #pragma unroll
                for (int kvb = 0; kvb < 4; ++kvb) {
                    int kvb0 = kv0 + kvb*16 + 4*g;
                    #pragma unroll
                    for (int r = 0; r < 4; ++r)
                        if (kvb0 + r > q) s[kvb][r] = -1e30f;
                }
            }

            // ---- max-free softmax: P = exp2(min(s,80)); masked -> 0
            #pragma unroll
            for (int kvb = 0; kvb < 4; ++kvb)
                #pragma unroll
                for (int r = 0; r < 4; ++r)
                    s[kvb][r] = __builtin_amdgcn_exp2f(fminf(s[kvb][r], 80.f));
            float p0 = (s[0][0] + s[0][1]) + (s[0][2] + s[0][3]);
            float p1 = (s[1][0] + s[1][1]) + (s[1][2] + s[1][3]);
            float p2 = (s[2][0] + s[2][1]) + (s[2][2] + s[2][3]);
            float p3 = (s[3][0] + s[3][1]) + (s[3][2] + s[3][3]);
            float ps = (p0 + p1) + (p2 + p3);
            ps += __shfl_xor(ps, 16);
            ps += __shfl_xor(ps, 32);
            l_run += ps;

            // ---- P -> LDS (per-wave; v_cvt_pk_bf16_f32 + ds_write_b64)
            #pragma unroll
            for (int kvb = 0; kvb < 4; ++kvb) {
                bf16_4 pk;
                pk[0] = (__bf16)s[kvb][0]; pk[1] = (__bf16)s[kvb][1];
                pk[2] = (__bf16)s[kvb][2]; pk[3] = (__bf16)s[kvb][3];
                *(bf16_4*)(Pw + lr*144 + kvb*32 + g*8) = pk;
            }
            asm volatile("s_waitcnt lgkmcnt(0)" ::: "memory");
            __builtin_amdgcn_sched_barrier(0);

            // ---- PV swapped: O^T += V^T(A) x P(B)
            __builtin_amdgcn_s_setprio(1);
            #pragma unroll
            for (int hh = 0; hh < 2; ++hh) {
                bf16_8 pa = *(const bf16_8*)(Pw + lr*144 + hh*64 + g*16);
                #pragma unroll
                for (int dt = 0; dt < 4; ++dt)
                    o[dt] = __builtin_amdgcn_mfma_f32_16x16x32_bf16(
                        vf[dt][hh], pa, o[dt], 0, 0, 0);
            }
            __builtin_amdgcn_s_setprio(0);
        }
    }

    // ---- epilogue: per-lane divide, LDS transpose, coalesced 128B row stores
    float linv = (l_run > 0.f) ? 1.f/l_run : 0.f;
    u16* ot = (u16*)Pw;                            // [d 64][q 16] stride 17
    #pragma unroll
    for (int dt = 0; dt < 4; ++dt)
        #pragma unroll
        for (int r = 0; r < 4; ++r)
            ot[(dt*16 + 4*g + r)*17 + lr] = f2bf(o[dt][r]*linv);
    asm volatile("s_waitcnt lgkmcnt(0)" ::: "memory");
    __builtin_amdgcn_sched_barrier(0);
    #pragma unroll
    for (int qq = 0; qq < 16; ++qq)
        AO[((size_t)(b*TT + qlo + qq))*D_MODEL + h*HDIM + lane] = ot[lane*17 + qq];
}

// ---------------------------------------------------------------- launch
extern "C" void kernel_launch(void* const* d_in, const int* in_sizes, int n_in,
                              void* d_out, int out_size, void* d_ws, size_t ws_size,
                              hipStream_t stream)
{
    const float* x  = (const float*)d_in[0];
    const unsigned char* mask = (const unsigned char*)d_in[1];
    const float* Wq = (const float*)d_in[2];
    const float* Wk = (const float*)d_in[3];
    const float* Wv = (const float*)d_in[4];
    const float* Wo = (const float*)d_in[5];
    float* out = (float*)d_out;

    char* ws = (char*)d_ws;
    u16* xb  = (u16*)(ws + 0);          // 8 MB (reused as AO after QKV)
    u16* wqb = (u16*)(ws + 8388608);
    u16* wkb = (u16*)(ws + 10485760);
    u16* wvb = (u16*)(ws + 12582912);
    u16* wob = (u16*)(ws + 14680064);
    u16* Qb  = (u16*)(ws + 16777216);
    u16* Kb  = (u16*)(ws + 25165824);
    u16* VTb = (u16*)(ws + 33554432);
    uint32_t* pmb = (uint32_t*)(ws + 41943040);   // 512 B mask bits
    u16* AOb = xb;

    cvtk<<<dim3(1024, 6), 256, 0, stream>>>(x, Wq, Wk, Wv, Wo, mask,
                                            xb, wqb, wkb, wvb, wob, pmb);
    gemm_qkv<<<dim3(512), 256, 0, stream>>>(xb, wqb, wkb, wvb, Qb, Kb, VTb);
    attn_fwd<<<dim3(32, 16), 512, 0, stream>>>(Qb, Kb, VTb, pmb, AOb);
    gemm_out<<<dim3(512), 256, 0, stream>>>(AOb, wob, out);
}

// Round 21
// 97.530 us; speedup vs baseline: 1.0253x; 1.0253x over previous
//
#include <hip/hip_runtime.h>
#include <hip/hip_bf16.h>
#include <stdint.h>

#define D_MODEL 1024
#define NHEADS  16
#define HDIM    64
#define BB      2
#define TT      2048
#define MROWS   (BB*TT)      // 4096
#define GK      1024         // reduction dim for all projections

typedef __bf16 bf16_8 __attribute__((ext_vector_type(8)));
typedef __bf16 bf16_4 __attribute__((ext_vector_type(4)));
typedef float  f32x4  __attribute__((ext_vector_type(4)));
typedef unsigned short u16;

__device__ __forceinline__ u16 f2bf(float f) {
    union { float f; uint32_t u; } c; c.f = f;
    uint32_t u = c.u;
    uint32_t r = (u + 0x7FFFu + ((u >> 16) & 1u)) >> 16;
    return (u16)r;
}
__device__ __forceinline__ uint32_t pk2bf(float a, float b) {
    return (uint32_t)f2bf(a) | ((uint32_t)f2bf(b) << 16);
}

__device__ __forceinline__ void gload16(const void* g, void* l) {
    __builtin_amdgcn_global_load_lds(
        (const __attribute__((address_space(1))) unsigned int*)g,
        (__attribute__((address_space(3))) unsigned int*)l,
        16, 0, 0);
}

// ---------------------------------------------------------------- convert
__global__ __launch_bounds__(256) void cvtk(
    const float* __restrict__ x,  const float* __restrict__ wq,
    const float* __restrict__ wk, const float* __restrict__ wv,
    const float* __restrict__ wo, const unsigned char* __restrict__ mk,
    u16* __restrict__ xb,  u16* __restrict__ wqb, u16* __restrict__ wkb,
    u16* __restrict__ wvb, u16* __restrict__ wob, uint32_t* __restrict__ pmb)
{
    int z = blockIdx.y;
    if (z == 5) {   // pack padding mask bits: pmb[b*64 + i], bit j = mask[b][32i+j]
        int gi = blockIdx.x*256 + threadIdx.x;
        if (gi < BB*TT/32) {
            uint32_t wv = 0;
            #pragma unroll
            for (int j = 0; j < 32; ++j)
                wv |= (mk[gi*32 + j] ? 1u : 0u) << j;
            pmb[gi] = wv;
        }
        return;
    }
    const float* in; u16* out; int n4;
    switch (z) {
        case 0: in = x;  out = xb;  n4 = MROWS*D_MODEL/4; break;
        case 1: in = wq; out = wqb; n4 = D_MODEL*D_MODEL/4; break;
        case 2: in = wk; out = wkb; n4 = D_MODEL*D_MODEL/4; break;
        case 3: in = wv; out = wvb; n4 = D_MODEL*D_MODEL/4; break;
        default: in = wo; out = wob; n4 = D_MODEL*D_MODEL/4; break;
    }
    for (int i = blockIdx.x*256 + threadIdx.x; i < n4; i += 1024*256) {
        float4 v = ((const float4*)in)[i];
        uint2 pk;
        pk.x = pk2bf(v.x, v.y);
        pk.y = pk2bf(v.z, v.w);
        ((uint2*)out)[i] = pk;
    }
}

// ---------------------------------------------------------------- fused QKV GEMM
// Block computes the SAME 128x64 output tile of Q, K, and V^T: A (x) staged
// once per K-step, shared by all three weight panels. 512 blocks = 2/CU.
__global__ __launch_bounds__(256) void gemm_qkv(
    const u16* __restrict__ xb,
    const u16* __restrict__ wqb, const u16* __restrict__ wkb, const u16* __restrict__ wvb,
    u16* __restrict__ Qb, u16* __restrict__ Kb, u16* __restrict__ VTb)
{
    __shared__ u16 As[128*64];        // 16 KB
    __shared__ u16 Bs[3][64*64];      // 24 KB
    const int tid  = threadIdx.x;
    const int lane = tid & 63, w = tid >> 6;
    const int g = lane >> 4, lr = lane & 15;
    const int xcd = blockIdx.x & 7, q_ = blockIdx.x >> 3;
    const int bn = q_ & 15, bm = (q_ >> 4)*8 + xcd;
    const int m0 = bm * 128, n0 = bn * 64;
    const u16* Wz[3] = { wqb, wkb, wvb };

    f32x4 acc[3][2][4];
    #pragma unroll
    for (int z = 0; z < 3; ++z)
        #pragma unroll
        for (int i = 0; i < 2; ++i)
            #pragma unroll
            for (int j = 0; j < 4; ++j)
                acc[z][i][j] = f32x4{0.f, 0.f, 0.f, 0.f};

    for (int kt = 0; kt < 16; ++kt) {
        int k0 = kt*64;
        #pragma unroll
        for (int r = 0; r < 4; ++r) {
            int o   = r*256 + tid;
            int row = o >> 3;
            int lc  = (o & 7) ^ (row & 7);
            gload16(xb + (size_t)(m0+row)*GK + k0 + lc*8,
                    (char*)As + (size_t)(r*256 + w*64)*16);
        }
        #pragma unroll
        for (int z = 0; z < 3; ++z)
            #pragma unroll
            for (int r = 0; r < 2; ++r) {
                int o   = r*256 + tid;
                int row = o >> 3;
                int lc  = (o & 7) ^ (row & 7);
                gload16(Wz[z] + (size_t)(n0+row)*GK + k0 + lc*8,
                        (char*)&Bs[z][0] + (size_t)(r*256 + w*64)*16);
            }
        __syncthreads();
        #pragma unroll
        for (int ks = 0; ks < 2; ++ks) {
            bf16_8 af[2];
            #pragma unroll
            for (int mt = 0; mt < 2; ++mt) {
                int row = w*32 + mt*16 + lr;
                int ch  = (ks*4 + g) ^ (row & 7);
                af[mt] = *(const bf16_8*)((const char*)As + row*128 + ch*16);
            }
            #pragma unroll
            for (int z = 0; z < 3; ++z) {
                bf16_8 bfr[4];
                #pragma unroll
                for (int nt = 0; nt < 4; ++nt) {
                    int row = nt*16 + lr;
                    int ch  = (ks*4 + g) ^ (row & 7);
                    bfr[nt] = *(const bf16_8*)((const char*)&Bs[z][0] + row*128 + ch*16);
                }
                #pragma unroll
                for (int mt = 0; mt < 2; ++mt)
                    #pragma unroll
                    for (int nt = 0; nt < 4; ++nt) {
                        if (z == 2)
                            acc[2][mt][nt] = __builtin_amdgcn_mfma_f32_16x16x32_bf16(
                                bfr[nt], af[mt], acc[2][mt][nt], 0, 0, 0);
                        else
                            acc[z][mt][nt] = __builtin_amdgcn_mfma_f32_16x16x32_bf16(
                                af[mt], bfr[nt], acc[z][mt][nt], 0, 0, 0);
                    }
            }
        }
        __syncthreads();
    }

    #pragma unroll
    for (int mt = 0; mt < 2; ++mt)
        #pragma unroll
        for (int nt = 0; nt < 4; ++nt)
            #pragma unroll
            for (int r = 0; r < 4; ++r) {
                int row = m0 + w*32 + mt*16 + g*4 + r;
                int col = n0 + nt*16 + lr;
                int b = row >> 11, t = row & (TT-1);
                int h = col >> 6,  d = col & 63;
                size_t qi = (((size_t)(b*NHEADS + h)*TT + t)*HDIM + d);
                Qb[qi] = f2bf(acc[0][mt][nt][r] * 0.18033688f);   // (1/8)*log2(e)
                Kb[qi] = f2bf(acc[1][mt][nt][r]);
                int nrow = n0 + nt*16 + g*4 + r;
                int mcol = m0 + w*32 + mt*16 + lr;
                int hv = nrow >> 6,  dv = nrow & 63;
                int bv = mcol >> 11, tv = mcol & (TT-1);
                VTb[(((size_t)(bv*NHEADS + hv)*HDIM + dv)*TT + tv)] = f2bf(acc[2][mt][nt][r]);
            }
}

// ---------------------------------------------------------------- out GEMM
// C(128x64) f32 tile of AO(4096x1024) * Wo(1024x1024)^T. 512 blocks = 2/CU.
__global__ __launch_bounds__(256) void gemm_out(
    const u16* __restrict__ AOb, const u16* __restrict__ wob, float* __restrict__ out)
{
    __shared__ u16 As[128*64];
    __shared__ u16 Bs[64*64];
    const int tid  = threadIdx.x;
    const int lane = tid & 63, w = tid >> 6;
    const int g = lane >> 4, lr = lane & 15;
    const int xcd = blockIdx.x & 7, q_ = blockIdx.x >> 3;
    const int bn = q_ & 15, bm = (q_ >> 4)*8 + xcd;
    const int m0 = bm * 128, n0 = bn * 64;

    f32x4 acc[2][4];
    #pragma unroll
    for (int i = 0; i < 2; ++i)
        #pragma unroll
        for (int j = 0; j < 4; ++j)
            acc[i][j] = f32x4{0.f, 0.f, 0.f, 0.f};

    for (int kt = 0; kt < 16; ++kt) {
        int k0 = kt*64;
        #pragma unroll
        for (int r = 0; r < 4; ++r) {
            int o   = r*256 + tid;
            int row = o >> 3;
            int lc  = (o & 7) ^ (row & 7);
            gload16(AOb + (size_t)(m0+row)*GK + k0 + lc*8,
                    (char*)As + (size_t)(r*256 + w*64)*16);
        }
        #pragma unroll
        for (int r = 0; r < 2; ++r) {
            int o   = r*256 + tid;
            int row = o >> 3;
            int lc  = (o & 7) ^ (row & 7);
            gload16(wob + (size_t)(n0+row)*GK + k0 + lc*8,
                    (char*)Bs + (size_t)(r*256 + w*64)*16);
        }
        __syncthreads();
        #pragma unroll
        for (int ks = 0; ks < 2; ++ks) {
            bf16_8 af[2], bfr[4];
            #pragma unroll
            for (int mt = 0; mt < 2; ++mt) {
                int row = w*32 + mt*16 + lr;
                int ch  = (ks*4 + g) ^ (row & 7);
                af[mt] = *(const bf16_8*)((const char*)As + row*128 + ch*16);
            }
            #pragma unroll
            for (int nt = 0; nt < 4; ++nt) {
                int row = nt*16 + lr;
                int ch  = (ks*4 + g) ^ (row & 7);
                bfr[nt] = *(const bf16_8*)((const char*)Bs + row*128 + ch*16);
            }
            #pragma unroll
            for (int mt = 0; mt < 2; ++mt)
                #pragma unroll
                for (int nt = 0; nt < 4; ++nt)
                    acc[mt][nt] = __builtin_amdgcn_mfma_f32_16x16x32_bf16(
                        af[mt], bfr[nt], acc[mt][nt], 0, 0, 0);
        }
        __syncthreads();
    }

    #pragma unroll
    for (int mt = 0; mt < 2; ++mt)
        #pragma unroll
        for (int nt = 0; nt < 4; ++nt)
            #pragma unroll
            for (int r = 0; r < 4; ++r) {
                int row = m0 + w*32 + mt*16 + g*4 + r;
                int col = n0 + nt*16 + lr;
                out[(size_t)row*D_MODEL + col] = acc[mt][nt][r];
            }
}

// ---------------------------------------------------------------- attention
// Best measured config (97.6 us total, reproduced twice): grid (32 bh, 16
// pairs) = 512 blocks of 8 waves; ~59.4 KB LDS -> 2/CU = 16 waves/CU.
// Wave owns ONE 16-row q-group (waves 0-3 heavy qtH=31-p, 4-7 light p);
// pair-balanced (49 iters/CU). K: 3 LDS buffers depth-2 prefetch; V: 2
// buffers depth-1; counted vmcnt(1). Max-free exp2 softmax; wave-uniform
// scalar mask loads.
__global__ __launch_bounds__(512, 4) void attn_fwd(
    const u16* __restrict__ Qb, const u16* __restrict__ Kb,
    const u16* __restrict__ VTb, const uint32_t* __restrict__ pmb,
    u16* __restrict__ AO)
{
    __shared__ u16 Ks[3][64*64];      // 24 KB
    __shared__ u16 Vs[2][64*64];      // 16 KB
    __shared__ u16 Pl[8][1152];       // 18 KB per-wave P / epilogue scratch

    const int tid = threadIdx.x, lane = tid & 63, w = tid >> 6;
    const int g = lane >> 4, lr = lane & 15;
    const int bh = blockIdx.x, yb = blockIdx.y;
    const int p  = (yb < 8) ? yb : 23 - yb;          // pair remap: CU gets (p,15-p)
    const int b = bh >> 4, h = bh & 15;
    const int qtH = 31 - p;
    const bool heavy = (w < 4);
    const int qlo = heavy ? (qtH*64 + w*16) : (p*64 + (w-4)*16);
    const int ta  = heavy ? qtH : p;                 // wave's last kv tile
    const int nt  = qtH + 1;

    const u16* Qh = Qb  + (size_t)bh*TT*HDIM;
    const u16* Kh = Kb  + (size_t)bh*TT*HDIM;
    const u16* Vh = VTb + (size_t)bh*HDIM*TT;
    const uint32_t* pmt = pmb + b*(TT/32);
    char* Pw = (char*)&Pl[w][0];

    // Q B-frags (pre-scaled by log2e/8): qf[dc] = Q[qlo+lr][dc*32+g*8..]
    bf16_8 qf[2];
    #pragma unroll
    for (int dc = 0; dc < 2; ++dc)
        qf[dc] = *(const bf16_8*)(Qh + (size_t)(qlo+lr)*HDIM + dc*32 + g*8);

    f32x4 o[4];                       // O^T: o[dt][r] = O[dt*16+4g+r][q=qlo+lr]
    #pragma unroll
    for (int i = 0; i < 4; ++i) o[i] = f32x4{0.f, 0.f, 0.f, 0.f};
    float l_run = 0.f;

    // cooperative stages: 512 threads x 16B = one 8KB tile per call
    auto STAGE_K = [&](int t, int buf) {
        int kv0 = t*64;
        int row = tid >> 3;                        // 0..63 (kv)
        int lc  = (tid & 7) ^ (row & 7);
        gload16(Kh + (size_t)(kv0+row)*HDIM + lc*8,
                (char*)&Ks[buf][0] + (size_t)(w*64)*16);
    };
    auto STAGE_V = [&](int t, int buf) {
        int kv0 = t*64;
        int row = tid >> 3;                        // 0..63 (d)
        int lc  = (tid & 7) ^ (row & 7);
        gload16(Vh + (size_t)row*TT + kv0 + lc*8,
                (char*)&Vs[buf][0] + (size_t)(w*64)*16);
    };

    // prologue: [K0, V0, K1] in flight (issue order matters for vmcnt)
    STAGE_K(0, 0);
    STAGE_V(0, 0);
    STAGE_K(1, 1);

    int kb = 0;                                    // K buffer of tile t
    for (int t = 0; t < nt; ++t) {
        if (t + 1 < nt) asm volatile("s_waitcnt vmcnt(1) lgkmcnt(0)" ::: "memory");
        else            asm volatile("s_waitcnt vmcnt(0) lgkmcnt(0)" ::: "memory");
        __builtin_amdgcn_s_barrier();
        if (t + 1 < nt) STAGE_V(t+1, (t+1) & 1);
        if (t + 2 < nt) { int nk = kb + 2; if (nk >= 3) nk -= 3; STAGE_K(t+2, nk); }

        if (t <= ta) {
            const int kv0 = t*64;
            const u16* Kc = &Ks[kb][0];
            const u16* Vc = &Vs[t & 1][0];
            // wave-uniform mask words (scalar loads; latency hides under QK)
            uint32_t mw0 = pmt[2*t], mw1 = pmt[2*t+1];

            // ---- QK^T swapped: s[kvb] lane: q=qlo+lr, kv=kv0+16kvb+4g+reg
            f32x4 s[4];
            __builtin_amdgcn_s_setprio(1);
            #pragma unroll
            for (int kvb = 0; kvb < 4; ++kvb) {
                int row = kvb*16 + lr;
                int sw  = row & 7;
                bf16_8 k0 = *(const bf16_8*)(Kc + row*64 + ((g    ) ^ sw)*8);
                bf16_8 k1 = *(const bf16_8*)(Kc + row*64 + ((4 + g) ^ sw)*8);
                f32x4 z = f32x4{0.f, 0.f, 0.f, 0.f};
                z = __builtin_amdgcn_mfma_f32_16x16x32_bf16(k0, qf[0], z, 0, 0, 0);
                z = __builtin_amdgcn_mfma_f32_16x16x32_bf16(k1, qf[1], z, 0, 0, 0);
                s[kvb] = z;
            }
            __builtin_amdgcn_s_setprio(0);

            // ---- V^T A-frags (LDS; latency hides under softmax)
            bf16_8 vf[4][2];
            #pragma unroll
            for (int dt = 0; dt < 4; ++dt)
                #pragma unroll
                for (int hh = 0; hh < 2; ++hh)
                    vf[dt][hh] = *(const bf16_8*)(Vc + (dt*16+lr)*64 + ((hh*4+g) ^ (lr&7))*8);

            // ---- padding mask (skipped when all-clear)
            if (mw0 | mw1) {
                uint64_t m64 = (uint64_t)mw0 | ((uint64_t)mw1 << 32);
                #pragma unroll
                for (int kvb = 0; kvb < 4; ++kvb) {
                    uint32_t nib = (uint32_t)(m64 >> (kvb*16 + 4*g)) & 0xFu;
                    #pragma unroll
                    for (int r = 0; r < 4; ++r)
                        if ((nib >> r) & 1) s[kvb][r] = -1e30f;
                }
            }
            // ---- causal mask (diagonal tile only)
            if (t == ta) {
                int q = qlo + lr;
                #pragma unroll
                for (int kvb = 0; kvb < 4; ++kvb) {
                    int kvb0 = kv0 + kvb*16 + 4*g;
                    #pragma unroll
                    for (int r = 0; r < 4; ++r)
                        if (kvb0 + r > q) s[kvb][r] = -1e30f;
                }
            }

            // ---- max-free softmax: P = exp2(min(s,80)); masked -> 0
            #pragma unroll
            for (int kvb = 0; kvb < 4; ++kvb)
                #pragma unroll
                for (int r = 0; r < 4; ++r)
                    s[kvb][r] = __builtin_amdgcn_exp2f(fminf(s[kvb][r], 80.f));
            float p0 = (s[0][0] + s[0][1]) + (s[0][2] + s[0][3]);
            float p1 = (s[1][0] + s[1][1]) + (s[1][2] + s[1][3]);
            float p2 = (s[2][0] + s[2][1]) + (s[2][2] + s[2][3]);
            float p3 = (s[3][0] + s[3][1]) + (s[3][2] + s[3][3]);
            float ps = (p0 + p1) + (p2 + p3);
            ps += __shfl_xor(ps, 16);
            ps += __shfl_xor(ps, 32);
            l_run += ps;

            // ---- P -> LDS (per-wave; v_cvt_pk_bf16_f32 + ds_write_b64)
            #pragma unroll
            for (int kvb = 0; kvb < 4; ++kvb) {
                bf16_4 pk;
                pk[0] = (__bf16)s[kvb][0]; pk[1] = (__bf16)s[kvb][1];
                pk[2] = (__bf16)s[kvb][2]; pk[3] = (__bf16)s[kvb][3];
                *(bf16_4*)(Pw + lr*144 + kvb*32 + g*8) = pk;
            }
            asm volatile("s_waitcnt lgkmcnt(0)" ::: "memory");
            __builtin_amdgcn_sched_barrier(0);

            // ---- PV swapped: O^T += V^T(A) x P(B)
            __builtin_amdgcn_s_setprio(1);
            #pragma unroll
            for (int hh = 0; hh < 2; ++hh) {
                bf16_8 pa = *(const bf16_8*)(Pw + lr*144 + hh*64 + g*16);
                #pragma unroll
                for (int dt = 0; dt < 4; ++dt)
                    o[dt] = __builtin_amdgcn_mfma_f32_16x16x32_bf16(
                        vf[dt][hh], pa, o[dt], 0, 0, 0);
            }
            __builtin_amdgcn_s_setprio(0);
        }

        ++kb; if (kb == 3) kb = 0;
    }

    // ---- epilogue: per-lane divide, LDS transpose, coalesced 128B row stores
    float linv = (l_run > 0.f) ? 1.f/l_run : 0.f;
    u16* ot = (u16*)Pw;                            // [d 64][q 16] stride 17
    #pragma unroll
    for (int dt = 0; dt < 4; ++dt)
        #pragma unroll
        for (int r = 0; r < 4; ++r)
            ot[(dt*16 + 4*g + r)*17 + lr] = f2bf(o[dt][r]*linv);
    asm volatile("s_waitcnt lgkmcnt(0)" ::: "memory");
    __builtin_amdgcn_sched_barrier(0);
    #pragma unroll
    for (int qq = 0; qq < 16; ++qq)
        AO[((size_t)(b*TT + qlo + qq))*D_MODEL + h*HDIM + lane] = ot[lane*17 + qq];
}

// ---------------------------------------------------------------- launch
extern "C" void kernel_launch(void* const* d_in, const int* in_sizes, int n_in,
                              void* d_out, int out_size, void* d_ws, size_t ws_size,
                              hipStream_t stream)
{
    const float* x  = (const float*)d_in[0];
    const unsigned char* mask = (const unsigned char*)d_in[1];
    const float* Wq = (const float*)d_in[2];
    const float* Wk = (const float*)d_in[3];
    const float* Wv = (const float*)d_in[4];
    const float* Wo = (const float*)d_in[5];
    float* out = (float*)d_out;

    char* ws = (char*)d_ws;
    u16* xb  = (u16*)(ws + 0);          // 8 MB (reused as AO after QKV)
    u16* wqb = (u16*)(ws + 8388608);
    u16* wkb = (u16*)(ws + 10485760);
    u16* wvb = (u16*)(ws + 12582912);
    u16* wob = (u16*)(ws + 14680064);
    u16* Qb  = (u16*)(ws + 16777216);
    u16* Kb  = (u16*)(ws + 25165824);
    u16* VTb = (u16*)(ws + 33554432);
    uint32_t* pmb = (uint32_t*)(ws + 41943040);   // 512 B mask bits
    u16* AOb = xb;

    cvtk<<<dim3(1024, 6), 256, 0, stream>>>(x, Wq, Wk, Wv, Wo, mask,
                                            xb, wqb, wkb, wvb, wob, pmb);
    gemm_qkv<<<dim3(512), 256, 0, stream>>>(xb, wqb, wkb, wvb, Qb, Kb, VTb);
    attn_fwd<<<dim3(32, 16), 512, 0, stream>>>(Qb, Kb, VTb, pmb, AOb);
    gemm_out<<<dim3(512), 256, 0, stream>>>(AOb, wob, out);
}